// Round 14
// baseline (111.440 us; speedup 1.0000x reference)
//
#include <hip/hip_runtime.h>
#include <hip/hip_bf16.h>

typedef float f32x4 __attribute__((ext_vector_type(4)));
typedef short s16x8 __attribute__((ext_vector_type(8)));

#define D_DIM 4096
#define NT 24            // 16-wide col tiles (global)
#define BM 128           // rows per block
#define NBODY 32         // bodies per block, BK=32 (K per block = 1024)
// LDS: B[8][1024] @ 0 (8 KB), A[8][1024] @ 8192 (8 KB) -> 16 KB single-buffered
#define AOFF 8192
// ws byte offsets
#define SINW_OFF 3145728u                 // sinws[4][8192] f32 = 128 KiB
#define PART_OFF 3276800u                 // part[4][8192][384] f16 = 24 MiB

__device__ __forceinline__ unsigned short f2bf(float f) {
    unsigned u = __float_as_uint(f);
    u += 0x7fffu + ((u >> 16) & 1u);   // RNE
    return (unsigned short)(u >> 16);
}

__device__ __forceinline__ void gload16(const void* g, void* l) {
    __builtin_amdgcn_global_load_lds(
        (const __attribute__((address_space(1))) unsigned int*)g,
        (__attribute__((address_space(3))) unsigned int*)l, 16, 0, 0);
}

__global__ __launch_bounds__(64) void reg_init_kernel(const float* __restrict__ C,
                                                      const float* __restrict__ Csin,
                                                      float* __restrict__ reg_out) {
    if (threadIdx.x == 0)
        reg_out[0] = 0.05f * (fabsf(C[0]) + fabsf(C[1]) + fabsf(C[2]) + fabsf(Csin[0]));
}

// Build W [4096 x 384] bf16, MFMA B-fragment-packed, slab-contiguous:
// chunk = (k>>5)*NT + (n>>4); lane = ((k&31)>>3)*16 | (n&15); j = k&7.
__global__ __launch_bounds__(64) void build_w_kernel(const float* __restrict__ U1,
                                                     const float* __restrict__ U2,
                                                     const float* __restrict__ U3,
                                                     unsigned short* __restrict__ W,
                                                     float* __restrict__ reg_out) {
    const int ks = blockIdx.x / NT;
    const int ct = blockIdx.x % NT;
    const int l  = threadIdx.x;
    const int n  = ct * 16 + (l & 15);
    const int kb = ks * 32 + ((l >> 4) << 3);

    const float* src;
    float scale;
    if (n < 64)       { src = U1 + n;                  scale = 0.01f / 262144.f; }
    else if (n < 128) { src = U2 + (n - 64);           scale = 0.01f / 524288.f; }
    else if (n < 192) { src = U2 + 262144 + (n - 128); scale = 0.01f / 524288.f; }
    else if (n < 256) { src = U3 + (n - 192);          scale = 0.01f / 786432.f; }
    else if (n < 320) { src = U3 + 262144 + (n - 256); scale = 0.01f / 786432.f; }
    else              { src = U3 + 524288 + (n - 320); scale = 0.01f / 786432.f; }

    unsigned short h[8];
    float sabs = 0.f;
#pragma unroll
    for (int j = 0; j < 8; ++j) {
        float u = src[(size_t)(kb + j) * 64];
        sabs += fabsf(u);
        h[j] = f2bf(u);
    }
    uint4 pk;
    pk.x = (unsigned)h[0] | ((unsigned)h[1] << 16);
    pk.y = (unsigned)h[2] | ((unsigned)h[3] << 16);
    pk.z = (unsigned)h[4] | ((unsigned)h[5] << 16);
    pk.w = (unsigned)h[6] | ((unsigned)h[7] << 16);
    *(uint4*)(W + ((size_t)blockIdx.x * 64 + l) * 8) = pk;

    sabs *= scale;
#pragma unroll
    for (int off = 32; off >= 1; off >>= 1)
        sabs += __shfl_xor(sabs, off, 64);
    if (l == 0) atomicAdd(reg_out, sabs);
}

// m97-geometry fused kernel. grid 768 = rb(64) x cb(3) x kq(4) -> 3 blocks/CU.
// Block: 256 thr = 4 waves (2 rg x 2 cgp); 128 rows x 128 cols x 1024 K,
// 32 bodies of BK=32. Wave tile 64x64 = 4x4 acc, 16 MFMA/body (m97's shape).
// Per body: B 8KB via gload_lds (2 chunks/wave); A 16KB f32 fused-staged
// (16 elems/thread: sin if cb==0, cvt, 2 ds_write_b128); __syncthreads;
// ds_read 4A+4B; 16 MFMA; __syncthreads. Drains covered by 3 co-resident
// blocks (m97/m114 mechanism). f16 partials x4 K-quarters.
__global__ __launch_bounds__(256, 3) void poly_main_kernel(const float* __restrict__ X,
                                                           const unsigned short* __restrict__ W,
                                                           _Float16* __restrict__ part,
                                                           float* __restrict__ sinws) {
    __shared__ __align__(16) char pool[16384];

    const int t    = threadIdx.x;
    const int lane = t & 63;
    const int wv   = t >> 6;          // 0..3
    const int rg   = wv >> 1;         // row half
    const int cgp  = wv & 1;          // col half
    const int bid  = blockIdx.x;
    const int rb   = bid / 12;
    const int cb   = (bid / 4) % 3;
    const int kq   = bid & 3;
    const int row0 = rb * BM;
    const bool doSin = (cb == 0);

    // A staging: thread -> (row sr, k-half h: 16 consecutive k)
    const int sr = t >> 1;            // 0..127
    const int h  = t & 1;
    const float* xp = X + (size_t)(row0 + sr) * D_DIM + kq * 1024 + h * 16;
    const int rf_s = sr >> 4;
    const int aw0 = AOFF + rf_s * 1024 + (((h * 2) * 16 + (sr & 15)) * 16);
    const int aw1 = aw0 + 256;

    f32x4 acc[4][4];
#pragma unroll
    for (int r = 0; r < 4; ++r)
#pragma unroll
        for (int c = 0; c < 4; ++c) acc[r][c] = (f32x4){0.f, 0.f, 0.f, 0.f};
    float sinacc = 0.f;

    for (int d = 0; d < NBODY; ++d) {
        // ---- issue B: wave wv loads chunks 2wv, 2wv+1 of this kslab ----
        {
            const unsigned short* g = W
                + ((size_t)(kq * 32 + d) * 24 + cb * 8 + 2 * wv) * 512 + lane * 8;
            gload16(g, pool + (2 * wv) * 1024);
            gload16(g + 512, pool + (2 * wv + 1) * 1024);
        }
        // ---- stage A: 16 f32 per thread (4 x f32x4), sin + cvt + 2 ds_write ----
        {
            const float* xb = xp + d * 32;
            f32x4 a = *(const f32x4*)xb;
            f32x4 b = *(const f32x4*)(xb + 4);
            f32x4 c = *(const f32x4*)(xb + 8);
            f32x4 e = *(const f32x4*)(xb + 12);
            if (doSin)
                sinacc += __sinf(a.x) + __sinf(a.y) + __sinf(a.z) + __sinf(a.w)
                        + __sinf(b.x) + __sinf(b.y) + __sinf(b.z) + __sinf(b.w)
                        + __sinf(c.x) + __sinf(c.y) + __sinf(c.z) + __sinf(c.w)
                        + __sinf(e.x) + __sinf(e.y) + __sinf(e.z) + __sinf(e.w);
            uint4 lo, hi;
            lo.x = (unsigned)f2bf(a.x) | ((unsigned)f2bf(a.y) << 16);
            lo.y = (unsigned)f2bf(a.z) | ((unsigned)f2bf(a.w) << 16);
            lo.z = (unsigned)f2bf(b.x) | ((unsigned)f2bf(b.y) << 16);
            lo.w = (unsigned)f2bf(b.z) | ((unsigned)f2bf(b.w) << 16);
            hi.x = (unsigned)f2bf(c.x) | ((unsigned)f2bf(c.y) << 16);
            hi.y = (unsigned)f2bf(c.z) | ((unsigned)f2bf(c.w) << 16);
            hi.z = (unsigned)f2bf(e.x) | ((unsigned)f2bf(e.y) << 16);
            hi.w = (unsigned)f2bf(e.z) | ((unsigned)f2bf(e.w) << 16);
            *(uint4*)(pool + aw0) = lo;
            *(uint4*)(pool + aw1) = hi;
        }
        __syncthreads();   // drains gload_lds (vmcnt) + ds_writes (lgkm)

        // ---- compute: 4 A-frags x 4 B-frags = 16 MFMA ----
        s16x8 bf0 = *(const s16x8*)(pool + (cgp * 4 + 0) * 1024 + lane * 16);
        s16x8 bf1 = *(const s16x8*)(pool + (cgp * 4 + 1) * 1024 + lane * 16);
        s16x8 bf2 = *(const s16x8*)(pool + (cgp * 4 + 2) * 1024 + lane * 16);
        s16x8 bf3 = *(const s16x8*)(pool + (cgp * 4 + 3) * 1024 + lane * 16);
#pragma unroll
        for (int r = 0; r < 4; ++r) {
            s16x8 af = *(const s16x8*)(pool + AOFF + (rg * 4 + r) * 1024 + lane * 16);
            acc[r][0] = __builtin_amdgcn_mfma_f32_16x16x32_bf16(af, bf0, acc[r][0], 0, 0, 0);
            acc[r][1] = __builtin_amdgcn_mfma_f32_16x16x32_bf16(af, bf1, acc[r][1], 0, 0, 0);
            acc[r][2] = __builtin_amdgcn_mfma_f32_16x16x32_bf16(af, bf2, acc[r][2], 0, 0, 0);
            acc[r][3] = __builtin_amdgcn_mfma_f32_16x16x32_bf16(af, bf3, acc[r][3], 0, 0, 0);
        }
        __syncthreads();   // LDS reads done before next body's overwrite
    }

    // ---- epilogue: f16 partial write + sin partial ----
    _Float16* pb = part + (size_t)kq * 8192 * 384;
    const int lr4 = (lane >> 4) << 2;
    const int lc  = lane & 15;
#pragma unroll
    for (int r = 0; r < 4; ++r)
#pragma unroll
        for (int c = 0; c < 4; ++c) {
            const int col = cb * 128 + cgp * 64 + c * 16 + lc;
#pragma unroll
            for (int i = 0; i < 4; ++i) {
                const int rl = rg * 64 + r * 16 + lr4 + i;
                pb[(size_t)(row0 + rl) * 384 + col] = (_Float16)acc[r][c][i];
            }
        }

    if (doSin) {
        sinacc += __shfl_xor(sinacc, 1);   // merge h=0/1 partners
        if (h == 0)
            sinws[(size_t)kq * 8192 + row0 + sr] = sinacc;
    }
}

// combine: sum 4 K-quarter partials + 4 sin partials; nonlinear epilogue.
__global__ __launch_bounds__(512) void combine_kernel(const _Float16* __restrict__ part,
                                                      const float* __restrict__ sinws,
                                                      const float* __restrict__ C,
                                                      const float* __restrict__ beta,
                                                      const float* __restrict__ Csin,
                                                      float* __restrict__ out) {
    const int t   = threadIdx.x;
    const int row = blockIdx.x * 32 + (t >> 4);
    const int cc  = t & 15;
    const size_t rbase = (size_t)row * 384;

    float t1 = 0.f, t2 = 0.f, t3 = 0.f;
#pragma unroll
    for (int j = 0; j < 4; ++j) {
        const int c = j * 16 + cc;
        float a1 = 0.f, a2 = 0.f, b2 = 0.f, a3 = 0.f, b3 = 0.f, c3 = 0.f;
#pragma unroll
        for (int qq = 0; qq < 4; ++qq) {
            const _Float16* p = part + (size_t)qq * 8192 * 384 + rbase;
            a1 += (float)p[c];
            a2 += (float)p[64 + c];
            b2 += (float)p[128 + c];
            a3 += (float)p[192 + c];
            b3 += (float)p[256 + c];
            c3 += (float)p[320 + c];
        }
        t1 += a1;
        t2 += a2 * b2;
        t3 += a3 * b3 * c3;
    }
#pragma unroll
    for (int off = 1; off < 16; off <<= 1) {
        t1 += __shfl_xor(t1, off, 16);
        t2 += __shfl_xor(t2, off, 16);
        t3 += __shfl_xor(t3, off, 16);
    }
    if (cc == 0) {
        const float s = sinws[row] + sinws[8192 + row]
                      + sinws[2 * 8192 + row] + sinws[3 * 8192 + row];
        out[row] = beta[0] + C[0] * t1 + C[1] * t2 + C[2] * t3 + Csin[0] * s;
    }
}

extern "C" void kernel_launch(void* const* d_in, const int* in_sizes, int n_in,
                              void* d_out, int out_size, void* d_ws, size_t ws_size,
                              hipStream_t stream) {
    const float* X   = (const float*)d_in[0];
    const float* U1  = (const float*)d_in[1];
    const float* U2  = (const float*)d_in[2];
    const float* U3  = (const float*)d_in[3];
    const float* Cc  = (const float*)d_in[4];
    const float* bet = (const float*)d_in[5];
    const float* Cs  = (const float*)d_in[6];
    float* out = (float*)d_out;

    unsigned short* W = (unsigned short*)d_ws;                  // 3 MiB, frag-packed
    float* sinws = (float*)((char*)d_ws + SINW_OFF);            // 128 KiB
    _Float16* part = (_Float16*)((char*)d_ws + PART_OFF);       // 24 MiB

    reg_init_kernel<<<1, 64, 0, stream>>>(Cc, Cs, out + 8192);
    build_w_kernel<<<128 * NT, 64, 0, stream>>>(U1, U2, U3, W, out + 8192);
    poly_main_kernel<<<768, 256, 0, stream>>>(X, W, part, sinws);
    combine_kernel<<<256, 512, 0, stream>>>(part, sinws, Cc, bet, Cs, out);
}